// Round 1
// baseline (598.629 us; speedup 1.0000x reference)
//
#include <hip/hip_runtime.h>
#include <math.h>

typedef float f4 __attribute__((ext_vector_type(4)));

#define PLANE (4096*4096)

// ---- output offsets (floats), concatenated return order ----
#define OUT_COL 0
#define OUT_ROW 262144
#define OUT_OBJ 524288
#define OUT_CV  524352
#define OUT_VC  34078784
#define OUT_VO  67633216
#define OUT_CO  67641408

// ---- workspace offsets (floats) ----
#define WS_VOACC 0        // [64]  v->o weighted-sum accumulator (atomic)
#define WS_COACC 64       // [64]  c->o weighted-sum accumulator (atomic)
#define WS_OBJ1  128      // [64]  obj after v->o update
#define WS_RDCV  256      // [4096] row_hidden . w_cv_row
#define WS_CDCV  4352     // [4096] col_hidden . w_cv_col
#define WS_RDVC  8448     // [4096] row_next . w_vc_row
#define WS_CDVC  12544    // [4096] col_hidden . w_vc_col
#define WS_VOUT  16640    // [4096*64] v_out
#define WS_COUT  278784   // [4096*64] c_out
#define WS_PART  540928   // [8][4096*64] j-split partials (8 MB)

__device__ __forceinline__ float sigf(float x) {
    return 1.0f / (1.0f + __expf(-x));
}

// ---------------------------------------------------------------------------
// Three 4096-long dot products: coldot_cv, coldot_vc, rowdot_cv.
// One wave per row; grid = 3*1024 blocks of 256 (4 waves).
__global__ __launch_bounds__(256) void k_dots(
    const float* __restrict__ col_hidden, const float* __restrict__ row_hidden,
    const float* __restrict__ w_cv_col, const float* __restrict__ w_vc_col,
    const float* __restrict__ w_cv_row,
    float* __restrict__ cdcv, float* __restrict__ cdvc, float* __restrict__ rdcv)
{
    const int gw = blockIdx.x * 4 + (threadIdx.x >> 6);
    const int lane = threadIdx.x & 63;
    const int which = gw >> 12;       // 0,1,2
    const int row = gw & 4095;
    const float* x; const float* w; float* dst;
    if (which == 0)      { x = col_hidden; w = w_cv_col; dst = cdcv; }
    else if (which == 1) { x = col_hidden; w = w_vc_col; dst = cdvc; }
    else                 { x = row_hidden; w = w_cv_row; dst = rdcv; }
    float v = x[row * 64 + lane] * w[lane];
    #pragma unroll
    for (int off = 32; off; off >>= 1) v += __shfl_down(v, off, 64);
    if (lane == 0) dst[row] = v;
}

// ---------------------------------------------------------------------------
// Attention over 4096 nodes: a[i] = sigmoid(X[i].wat[0:64] + supp[i].wat[64:66]
//  + obj.wat[66:130] + b); accum[h] += sum_i a[i]*X[i,h].
// Optionally also computes dextra[i] = X[i] . wextra (fused rowdot_vc).
// grid = 16 blocks x 256 threads; accum must be pre-zeroed.
__global__ __launch_bounds__(256) void k_attn(
    const float* __restrict__ X, const float* __restrict__ supp,
    const float* __restrict__ obj, const float* __restrict__ wat,
    const float* __restrict__ bat, float* __restrict__ accum,
    const float* __restrict__ wextra, float* __restrict__ dextra)
{
    __shared__ float sA[256];
    __shared__ float sAcc[64];
    const int t = threadIdx.x;
    const int i = blockIdx.x * 256 + t;
    float x = bat[0] + supp[i*2] * wat[64] + supp[i*2+1] * wat[65];
    float d = 0.f;
    for (int h = 0; h < 64; ++h) {
        x += obj[h] * wat[66 + h];
        float xv = X[i*64 + h];
        x += xv * wat[h];
        if (wextra) d += xv * wextra[h];
    }
    if (dextra) dextra[i] = d;
    sA[t] = sigf(x);
    if (t < 64) sAcc[t] = 0.f;
    __syncthreads();
    const int w = t >> 6, h = t & 63;
    const int base = blockIdx.x * 256 + w * 64;
    float partial = 0.f;
    for (int j = 0; j < 64; ++j)
        partial += sA[w*64 + j] * X[(base + j)*64 + h];
    atomicAdd(&sAcc[h], partial);
    __syncthreads();
    if (t < 64) atomicAdd(&accum[t], sAcc[t]);
}

// ---------------------------------------------------------------------------
// obj update: dst[h] = relu(sum_k left[k]*W[k,h] + right[k]*W[64+k,h]); 1x64.
__global__ void k_obj(const float* __restrict__ left, const float* __restrict__ right,
                      const float* __restrict__ W, float* __restrict__ dst)
{
    const int h = threadIdx.x;
    float acc = 0.f;
    for (int k = 0; k < 64; ++k) acc += left[k]  * W[k*64 + h];
    for (int k = 0; k < 64; ++k) acc += right[k] * W[(64+k)*64 + h];
    dst[h] = fmaxf(acc, 0.f);
}

// ---------------------------------------------------------------------------
// Big fused kernel: masked pairwise sigmoid scores + score @ B + supp passthrough.
//   out(i,h) = sum_j [supp0(i,j)!=0] sig(rdot[i]+cdot[j]+w0*supp0+w1*supp1+b) * B(j,h)
// Block: 64 rows x 512-wide j slice. grid = 64 * 8 = 512. Partials to part[bj].
__global__ __launch_bounds__(256) void k_big(
    const float* __restrict__ supp0, const float* __restrict__ supp1,
    const float* __restrict__ Bm,
    const float* __restrict__ rdot, const float* __restrict__ cdot,
    const float* __restrict__ wsup, const float* __restrict__ bias,
    float* __restrict__ part, float* __restrict__ pass0, float* __restrict__ pass1)
{
    __shared__ __align__(16) float sS[64][68];   // score tile, padded row stride (16B-aligned)
    __shared__ __align__(16) float sB[64][64];   // B tile
    const int t  = threadIdx.x;
    const int bi = blockIdx.x & 63;
    const int bj = blockIdx.x >> 6;
    const int i0 = bi * 64;
    const int jl4 = (t & 15) * 4;
    const int ilb = t >> 4;            // 0..15
    const int rgrp = ilb;
    const int h0 = jl4;
    const float w0 = wsup[0], w1 = wsup[1], bv = bias[0];

    f4 acc0 = 0.f, acc1 = 0.f, acc2 = 0.f, acc3 = 0.f;

    for (int tile = 0; tile < 8; ++tile) {
        const int jt = bj * 512 + tile * 64;
        // stage B tile (contiguous 16 KB)
        {
            const f4* src = (const f4*)(Bm + (size_t)jt * 64);
            f4* dstp = (f4*)&sB[0][0];
            dstp[t]       = src[t];
            dstp[t + 256] = src[t + 256];
            dstp[t + 512] = src[t + 512];
            dstp[t + 768] = src[t + 768];
        }
        // score tile + passthrough copy
        const f4 cd = *(const f4*)(cdot + jt + jl4);
        #pragma unroll
        for (int k = 0; k < 4; ++k) {
            const int il = ilb + 16 * k;
            const size_t idx = (size_t)(i0 + il) * 4096 + jt + jl4;
            f4 a0 = *(const f4*)(supp0 + idx);
            f4 a1 = *(const f4*)(supp1 + idx);
            *(f4*)(pass0 + idx) = a0;
            *(f4*)(pass1 + idx) = a1;
            const float rd = rdot[i0 + il];
            f4 lg = rd + cd + w0 * a0 + w1 * a1 + bv;
            f4 s;
            s.x = (a0.x != 0.f) ? sigf(lg.x) : 0.f;
            s.y = (a0.y != 0.f) ? sigf(lg.y) : 0.f;
            s.z = (a0.z != 0.f) ? sigf(lg.z) : 0.f;
            s.w = (a0.w != 0.f) ? sigf(lg.w) : 0.f;
            *(f4*)&sS[il][jl4] = s;
        }
        __syncthreads();
        // rank-64 update: 4 rows x 4 h per thread, all LDS reads are b128
        #pragma unroll
        for (int jj = 0; jj < 64; jj += 4) {
            f4 b0 = *(const f4*)&sB[jj + 0][h0];
            f4 b1 = *(const f4*)&sB[jj + 1][h0];
            f4 b2 = *(const f4*)&sB[jj + 2][h0];
            f4 b3 = *(const f4*)&sB[jj + 3][h0];
            { f4 s = *(const f4*)&sS[rgrp*4 + 0][jj]; acc0 += s.x*b0 + s.y*b1 + s.z*b2 + s.w*b3; }
            { f4 s = *(const f4*)&sS[rgrp*4 + 1][jj]; acc1 += s.x*b0 + s.y*b1 + s.z*b2 + s.w*b3; }
            { f4 s = *(const f4*)&sS[rgrp*4 + 2][jj]; acc2 += s.x*b0 + s.y*b1 + s.z*b2 + s.w*b3; }
            { f4 s = *(const f4*)&sS[rgrp*4 + 3][jj]; acc3 += s.x*b0 + s.y*b1 + s.z*b2 + s.w*b3; }
        }
        __syncthreads();
    }
    float* pb = part + (size_t)bj * 262144 + (size_t)i0 * 64;
    *(f4*)(pb + (rgrp*4 + 0)*64 + h0) = acc0;
    *(f4*)(pb + (rgrp*4 + 1)*64 + h0) = acc1;
    *(f4*)(pb + (rgrp*4 + 2)*64 + h0) = acc2;
    *(f4*)(pb + (rgrp*4 + 3)*64 + h0) = acc3;
}

// ---------------------------------------------------------------------------
// Reduce 8 j-split partials -> dst ([4096*64] floats, float4-strided).
__global__ __launch_bounds__(256) void k_reduce(const float* __restrict__ part,
                                                float* __restrict__ dst)
{
    const int idx = blockIdx.x * 256 + threadIdx.x;   // 0..65535 (f4 units)
    const f4* p = (const f4*)part;
    f4 s = p[idx];
    #pragma unroll
    for (int j = 1; j < 8; ++j) s += p[j * 65536 + idx];
    ((f4*)dst)[idx] = s;
}

// ---------------------------------------------------------------------------
// Two-layer node update:
//   mid = relu([objx | base[n]] @ W1);  dst[n] = relu([mid | accin[n]] @ W2)
// One wave per node row; grid = 1024 blocks x 256.
__global__ __launch_bounds__(256) void k_mlp2(
    const float* __restrict__ objx, const float* __restrict__ base,
    const float* __restrict__ W1, const float* __restrict__ accin,
    const float* __restrict__ W2, float* __restrict__ dst)
{
    __shared__ float mid[4][64];
    const int t = threadIdx.x, w = t >> 6, h = t & 63;
    const int n = blockIdx.x * 4 + w;
    float m = 0.f;
    for (int k = 0; k < 64; ++k) m += objx[k] * W1[k*64 + h];
    for (int k = 0; k < 64; ++k) m += base[n*64 + k] * W1[(64+k)*64 + h];
    mid[w][h] = fmaxf(m, 0.f);
    __syncthreads();
    float o = 0.f;
    for (int k = 0; k < 64; ++k) o += mid[w][k] * W2[k*64 + h];
    for (int k = 0; k < 64; ++k) o += accin[n*64 + k] * W2[(64+k)*64 + h];
    dst[n*64 + h] = fmaxf(o, 0.f);
}

// ---------------------------------------------------------------------------
// Copy vo_supp (8192) and co_supp (8192) to output tail. grid 16 x 256, f4 units.
__global__ void k_copy_small(const float* __restrict__ a, const float* __restrict__ b,
                             float* __restrict__ da, float* __restrict__ db)
{
    const int idx = blockIdx.x * 256 + threadIdx.x;   // 0..4095
    if (idx < 2048) ((f4*)da)[idx] = ((const f4*)a)[idx];
    else            ((f4*)db)[idx - 2048] = ((const f4*)b)[idx - 2048];
}

extern "C" void kernel_launch(void* const* d_in, const int* in_sizes, int n_in,
                              void* d_out, int out_size, void* d_ws, size_t ws_size,
                              hipStream_t stream)
{
    const float* col_hidden = (const float*)d_in[0];
    const float* row_hidden = (const float*)d_in[1];
    const float* obj_hidden = (const float*)d_in[2];
    const float* cv_supp    = (const float*)d_in[3];
    const float* vc_supp    = (const float*)d_in[4];
    const float* vo_supp    = (const float*)d_in[5];
    const float* co_supp    = (const float*)d_in[6];
    const float* W_vo       = (const float*)d_in[7];
    const float* W_oc       = (const float*)d_in[8];
    const float* W_vc       = (const float*)d_in[9];
    const float* W_co       = (const float*)d_in[10];
    const float* W_ov       = (const float*)d_in[11];
    const float* W_cv       = (const float*)d_in[12];
    const float* w_attn_vo  = (const float*)d_in[13];
    const float* b_attn_vo  = (const float*)d_in[14];
    const float* w_attn_co  = (const float*)d_in[15];
    const float* b_attn_co  = (const float*)d_in[16];
    const float* w_cv_col   = (const float*)d_in[17];
    const float* w_cv_supp  = (const float*)d_in[18];
    const float* w_cv_row   = (const float*)d_in[19];
    const float* b_cv       = (const float*)d_in[20];
    const float* w_vc_row   = (const float*)d_in[21];
    const float* w_vc_supp  = (const float*)d_in[22];
    const float* w_vc_col   = (const float*)d_in[23];
    const float* b_vc       = (const float*)d_in[24];

    float* out = (float*)d_out;
    float* ws  = (float*)d_ws;

    // zero the two 64-float atomic accumulators (ws is poisoned each call)
    hipMemsetAsync(ws, 0, 128 * sizeof(float), stream);

    // precompute row/col dot terms (independent of obj chain)
    k_dots<<<3072, 256, 0, stream>>>(col_hidden, row_hidden, w_cv_col, w_vc_col, w_cv_row,
                                     ws + WS_CDCV, ws + WS_CDVC, ws + WS_RDCV);
    // v -> o attention + reduce
    k_attn<<<16, 256, 0, stream>>>(col_hidden, vo_supp, obj_hidden, w_attn_vo, b_attn_vo,
                                   ws + WS_VOACC, nullptr, nullptr);
    k_obj<<<1, 64, 0, stream>>>(obj_hidden, ws + WS_VOACC, W_vo, ws + WS_OBJ1);
    // v -> c: big masked matmul (fused cv_supp passthrough)
    k_big<<<512, 256, 0, stream>>>(cv_supp, cv_supp + PLANE, col_hidden,
                                   ws + WS_RDCV, ws + WS_CDCV, w_cv_supp, b_cv,
                                   ws + WS_PART, out + OUT_CV, out + OUT_CV + PLANE);
    k_reduce<<<256, 256, 0, stream>>>(ws + WS_PART, ws + WS_VOUT);
    k_mlp2<<<1024, 256, 0, stream>>>(ws + WS_OBJ1, row_hidden, W_oc, ws + WS_VOUT, W_vc,
                                     out + OUT_ROW);
    // c -> o attention (+ fused rowdot_vc over row_next)
    k_attn<<<16, 256, 0, stream>>>(out + OUT_ROW, co_supp, ws + WS_OBJ1, w_attn_co, b_attn_co,
                                   ws + WS_COACC, w_vc_row, ws + WS_RDVC);
    k_obj<<<1, 64, 0, stream>>>(ws + WS_OBJ1, ws + WS_COACC, W_co, out + OUT_OBJ);
    // c -> v: big masked matmul (fused vc_supp passthrough)
    k_big<<<512, 256, 0, stream>>>(vc_supp, vc_supp + PLANE, out + OUT_ROW,
                                   ws + WS_CDVC, ws + WS_RDVC, w_vc_supp, b_vc,
                                   ws + WS_PART, out + OUT_VC, out + OUT_VC + PLANE);
    k_reduce<<<256, 256, 0, stream>>>(ws + WS_PART, ws + WS_COUT);
    k_mlp2<<<1024, 256, 0, stream>>>(out + OUT_OBJ, col_hidden, W_ov, ws + WS_COUT, W_cv,
                                     out + OUT_COL);
    // passthrough of the small supp tensors
    k_copy_small<<<16, 256, 0, stream>>>(vo_supp, co_supp, out + OUT_VO, out + OUT_CO);
}